// Round 9
// baseline (396.785 us; speedup 1.0000x reference)
//
#include <hip/hip_runtime.h>
#include <math.h>

#define B_  8
#define T_  4096
#define H_  512
#define FREQ 513
#define NW  576            // padded f (9 tiles of 64)
#define KE  576            // spec K: interleaved [re,im] pairs, padded; 9 tiles of 64
#define NFFT 1024
#define HOP 256
#define PAD 384
#define OUTB 1048576
#define CLAMP_MAXV 100.0f
#define SE_E ((size_t)T_ * KE)     // spec elems per batch per buffer (= 9 * T_ * 64)
#define EO_E ((size_t)T_ * NFFT)   // EO floats per batch

typedef __attribute__((ext_vector_type(8))) short bf16x8;
typedef __attribute__((ext_vector_type(4))) float f32x4;

__device__ inline ushort f2bf(float v) {
    union { float f; unsigned u; } x; x.f = v;
    unsigned r = x.u + 0x7FFFu + ((x.u >> 16) & 1u);   // RNE
    return (ushort)(r >> 16);
}
__device__ inline float bf2f(ushort h) {
    union { unsigned u; float f; } x; x.u = ((unsigned)h) << 16;
    return x.f;
}

#define GLOAD_LDS16(g, l) __builtin_amdgcn_global_load_lds( \
    (const __attribute__((address_space(1))) unsigned int*)(g), \
    (__attribute__((address_space(3))) unsigned int*)(l), 16, 0, 0)

// ---------------- basis: Ab[r][c]; r<512: E half (k=2kk), r>=512: O half (k=2kk+1) ----------------
__global__ void basis_kernel(ushort* __restrict__ Abh, ushort* __restrict__ Abl) {
    int idx = blockIdx.x * 256 + threadIdx.x;   // [0, 1024*576)
    int r = idx / KE, c = idx - r * KE;
    int np = (r < 512) ? r : (r - 512);
    int kk = c >> 1;
    int k = (r < 512) ? (2 * kk) : (2 * kk + 1);
    float v = 0.f;
    bool valid = (r < 512) ? (kk <= 256) : (kk <= 255);
    if (valid) {
        int m = (np * k) & (NFFT - 1);
        float a = (float)m * 6.135923151542565e-3f;       // 2*pi/1024
        float sc = ((k == 0) || (k == 512)) ? (1.0f / NFFT) : (2.0f / NFFT);
        v = ((c & 1) ? -sinf(a) : cosf(a)) * sc;
    }
    ushort h = f2bf(v);
    Abh[idx] = h;
    Abl[idx] = f2bf(v - bf2f(h));
}

// ---------------- W prep: Wm/Wp [f(576)][k(512)] hi/lo bf16 ----------------
__global__ void prepw_kernel(const float* __restrict__ W,
                             ushort* __restrict__ Wmh, ushort* __restrict__ Wml,
                             ushort* __restrict__ Wph, ushort* __restrict__ Wpl) {
    int idx = blockIdx.x * 256 + threadIdx.x;
    if (idx >= NW * H_) return;
    int k = idx / NW, f = idx - k * NW;
    float vm = 0.f, vp = 0.f;
    if (f < FREQ) {
        vm = W[(size_t)k * (2 * FREQ) + f];
        vp = W[(size_t)k * (2 * FREQ) + FREQ + f];
    }
    size_t dst = (size_t)f * H_ + k;
    ushort h1 = f2bf(vm); Wmh[dst] = h1; Wml[dst] = f2bf(vm - bf2f(h1));
    ushort h2 = f2bf(vp); Wph[dst] = h2; Wpl[dst] = f2bf(vp - bf2f(h2));
}

// ---------------- GEMM A (MFMA split-bf16): h = x@W + b, x converted in-kernel ----------------
// grid: (bcount*32, 9); block 256 (4 waves 2x2). Tile 128 t x 64 f, K=512.
// Spec written TILED: buf[b][ftile][t][64] -> dense 16KB contiguous per block per buffer.
__global__ __launch_bounds__(256) void gemm_a_mfma(
    const float* __restrict__ x,
    const ushort* __restrict__ Wmh, const ushort* __restrict__ Wml,
    const ushort* __restrict__ Wph, const ushort* __restrict__ Wpl,
    const float* __restrict__ bias,
    ushort* __restrict__ SEh, ushort* __restrict__ SEl,
    ushort* __restrict__ SOh, ushort* __restrict__ SOl, int b0)
{
    // staging: x hi/lo 2x4096 ushorts + W 4x2048; epilogue reuses 2 x 9216
    __shared__ __attribute__((aligned(16))) ushort SH[18432];

    const int tid = threadIdx.x;
    const int lane = tid & 63;
    const int w = tid >> 6;
    const int wr = w >> 1, wc = w & 1;
    const int m0 = blockIdx.x * 128;     // chunk-local row
    const int f0 = blockIdx.y * 64;

    const int srow = tid >> 2;
    const int ssel = ((tid & 3) ^ ((tid >> 3) & 3)) * 8;   // swizzled chunk (write & gload-src)
    const int arow = lane & 15;
    const int kch  = (((lane >> 4) ^ ((arow >> 1) & 3))) * 8;

    const int xrow = tid >> 2;           // 0..63 within q-half
    const int xcol = (tid & 3) * 8;      // 8 floats per thread

    f32x4 accM[4][2] = {};
    f32x4 accP[4][2] = {};

    const size_t xbase = (size_t)b0 * T_ + m0;
    char* pSH = (char*)SH;

    for (int k0 = 0; k0 < H_; k0 += 32) {
        // x: global fp32 -> regs (issue early)
        float4 xa[2][2];
        #pragma unroll
        for (int q = 0; q < 2; ++q) {
            const float* xr = x + (xbase + q * 64 + xrow) * H_ + k0 + xcol;
            xa[q][0] = *reinterpret_cast<const float4*>(xr);
            xa[q][1] = *reinterpret_cast<const float4*>(xr + 4);
        }
        // W: global -> LDS direct
        size_t wo = (size_t)(f0 + srow) * H_ + k0 + ssel;
        GLOAD_LDS16(Wmh + wo, pSH + 16384 + w * 1024);
        GLOAD_LDS16(Wml + wo, pSH + 20480 + w * 1024);
        GLOAD_LDS16(Wph + wo, pSH + 24576 + w * 1024);
        GLOAD_LDS16(Wpl + wo, pSH + 28672 + w * 1024);
        // convert x -> hi/lo bf16, ds_write into swizzled slots
        #pragma unroll
        for (int q = 0; q < 2; ++q) {
            float xv[8];
            *reinterpret_cast<float4*>(&xv[0]) = xa[q][0];
            *reinterpret_cast<float4*>(&xv[4]) = xa[q][1];
            bf16x8 vh, vl;
            #pragma unroll
            for (int e = 0; e < 8; ++e) {
                ushort h = f2bf(xv[e]);
                vh[e] = (short)h;
                vl[e] = (short)f2bf(xv[e] - bf2f(h));
            }
            int lo = (q * 64 + xrow) * 32 + ssel;
            *reinterpret_cast<bf16x8*>(&SH[lo]) = vh;          // sxh @ ushort 0
            *reinterpret_cast<bf16x8*>(&SH[4096 + lo]) = vl;   // sxl @ ushort 4096
        }
        __syncthreads();
        bf16x8 ah[4], al[4], bmh[2], bml[2], bph[2], bpl[2];
        #pragma unroll
        for (int i = 0; i < 4; ++i) {
            int r = (wr * 64 + i * 16 + arow) * 32 + kch;
            ah[i] = *reinterpret_cast<const bf16x8*>(&SH[r]);
            al[i] = *reinterpret_cast<const bf16x8*>(&SH[4096 + r]);
        }
        #pragma unroll
        for (int j = 0; j < 2; ++j) {
            int r = (wc * 32 + j * 16 + arow) * 32 + kch;
            bmh[j] = *reinterpret_cast<const bf16x8*>(&SH[8192 + r]);
            bml[j] = *reinterpret_cast<const bf16x8*>(&SH[10240 + r]);
            bph[j] = *reinterpret_cast<const bf16x8*>(&SH[12288 + r]);
            bpl[j] = *reinterpret_cast<const bf16x8*>(&SH[14336 + r]);
        }
        #pragma unroll
        for (int i = 0; i < 4; ++i)
            #pragma unroll
            for (int j = 0; j < 2; ++j) {
                accM[i][j] = __builtin_amdgcn_mfma_f32_16x16x32_bf16(ah[i], bmh[j], accM[i][j], 0, 0, 0);
                accM[i][j] = __builtin_amdgcn_mfma_f32_16x16x32_bf16(ah[i], bml[j], accM[i][j], 0, 0, 0);
                accM[i][j] = __builtin_amdgcn_mfma_f32_16x16x32_bf16(al[i], bmh[j], accM[i][j], 0, 0, 0);
                accP[i][j] = __builtin_amdgcn_mfma_f32_16x16x32_bf16(ah[i], bph[j], accP[i][j], 0, 0, 0);
                accP[i][j] = __builtin_amdgcn_mfma_f32_16x16x32_bf16(ah[i], bpl[j], accP[i][j], 0, 0, 0);
                accP[i][j] = __builtin_amdgcn_mfma_f32_16x16x32_bf16(al[i], bph[j], accP[i][j], 0, 0, 0);
            }
        __syncthreads();
    }

    // ---- epilogue: nonlinearity in place, then 2-pass LDS transpose (hi, lo) ----
    const int ccol = lane & 15;
    const int rbase = (lane >> 4) * 4;
    const int b_local = m0 >> 12;
    const int t00blk = m0 & (T_ - 1);
    const size_t specoff = (size_t)b_local * SE_E;
    const size_t tilebase = (size_t)blockIdx.y * T_ * 64;   // ftile offset within batch

    #pragma unroll
    for (int j = 0; j < 2; ++j) {
        int f = f0 + wc * 32 + j * 16 + ccol;
        bool live = (f < FREQ);
        float bm = live ? bias[f] : 0.f;
        float bp = live ? bias[FREQ + f] : 0.f;
        #pragma unroll
        for (int i = 0; i < 4; ++i)
            #pragma unroll
            for (int r = 0; r < 4; ++r) {
                float re = 0.f, im = 0.f;
                if (live) {
                    float mag = fminf(__expf(accM[i][j][r] + bm), CLAMP_MAXV);
                    float phv = accP[i][j][r] + bp;
                    float sp, cp; sincosf(phv, &sp, &cp);
                    re = mag * cp; im = mag * sp;
                }
                accM[i][j][r] = re; accP[i][j][r] = im;
            }
    }

    const int row0 = tid >> 3;     // 0..31
    const int c8 = (tid & 7) * 8;  // ushort chunk within 64
    #pragma unroll
    for (int pass = 0; pass < 2; ++pass) {
        #pragma unroll
        for (int j = 0; j < 2; ++j) {
            int u = wc * 32 + j * 16 + ccol;     // 0..63 within f-tile
            int par = u & 1;                     // 0 -> SE, 1 -> SO
            int kl = u & ~1;                     // kappa within tile (even)
            #pragma unroll
            for (int i = 0; i < 4; ++i) {
                #pragma unroll
                for (int r = 0; r < 4; ++r) {
                    float re = accM[i][j][r], im = accP[i][j][r];
                    ushort rv, iv;
                    if (pass == 0) {
                        rv = f2bf(re); iv = f2bf(im);
                    } else {
                        ushort rh = f2bf(re), ih = f2bf(im);
                        rv = f2bf(re - bf2f(rh)); iv = f2bf(im - bf2f(ih));
                    }
                    int tl = wr * 64 + i * 16 + rbase + r;
                    *reinterpret_cast<ushort2*>(&SH[par * 9216 + tl * 72 + kl]) =
                        make_ushort2(rv, iv);
                }
            }
        }
        __syncthreads();
        ushort* d0 = (pass ? SEl : SEh) + specoff + tilebase;
        ushort* d1 = (pass ? SOl : SOh) + specoff + tilebase;
        #pragma unroll
        for (int q2 = 0; q2 < 4; ++q2) {
            int row = q2 * 32 + row0;
            bf16x8 v0 = *reinterpret_cast<const bf16x8*>(&SH[row * 72 + c8]);
            bf16x8 v1 = *reinterpret_cast<const bf16x8*>(&SH[9216 + row * 72 + c8]);
            *reinterpret_cast<bf16x8*>(&d0[(size_t)(t00blk + row) * 64 + c8]) = v0;
            *reinterpret_cast<bf16x8*>(&d1[(size_t)(t00blk + row) * 64 + c8]) = v1;
        }
        if (pass == 0) __syncthreads();
    }
}

// ---------------- stage 1 GEMM (MFMA): EO[b][t][n''] = basis . spec (tiled spec reads) ----------
// grid: (32 t-tiles, 8 n-tiles, bcount); block 256 (4 waves 2x2). Tile 128 n x 128 t, K=576.
__global__ __launch_bounds__(256) void gemm_eo_mfma(
    const ushort* __restrict__ Abh, const ushort* __restrict__ Abl,
    const ushort* __restrict__ SEh, const ushort* __restrict__ SEl,
    const ushort* __restrict__ SOh, const ushort* __restrict__ SOl,
    float* __restrict__ EO)
{
    __shared__ __attribute__((aligned(16))) ushort sAh[128 * 32];
    __shared__ __attribute__((aligned(16))) ushort sAl[128 * 32];
    __shared__ __attribute__((aligned(16))) ushort sBh[128 * 32];
    __shared__ __attribute__((aligned(16))) ushort sBl[128 * 32];
    const int tid = threadIdx.x;
    const int lane = tid & 63;
    const int w = tid >> 6;
    const int wr = w >> 1, wc = w & 1;
    const int t0 = blockIdx.x * 128;
    const int n0 = blockIdx.y * 128;
    const int b_local = blockIdx.z;

    const ushort* Bsh = ((n0 < 512) ? SEh : SOh) + (size_t)b_local * SE_E;
    const ushort* Bsl = ((n0 < 512) ? SEl : SOl) + (size_t)b_local * SE_E;

    const int srow = tid >> 2;
    const int ssel = ((tid & 3) ^ ((tid >> 3) & 3)) * 8;
    const int arow = lane & 15;
    const int kch  = (((lane >> 4) ^ ((arow >> 1) & 3))) * 8;

    f32x4 acc[4][4] = {};
    char* pAh = (char*)sAh; char* pAl = (char*)sAl;
    char* pBh = (char*)sBh; char* pBl = (char*)sBl;

    for (int k0 = 0; k0 < KE; k0 += 32) {
        #pragma unroll
        for (int q = 0; q < 2; ++q) {
            size_t ao = (size_t)(n0 + q * 64 + srow) * KE + k0 + ssel;
            GLOAD_LDS16(Abh + ao, pAh + q * 4096 + w * 1024);
            GLOAD_LDS16(Abl + ao, pAl + q * 4096 + w * 1024);
            size_t bo = ((size_t)(k0 >> 6) * T_ + t0 + q * 64 + srow) * 64 + (k0 & 32) + ssel;
            GLOAD_LDS16(Bsh + bo, pBh + q * 4096 + w * 1024);
            GLOAD_LDS16(Bsl + bo, pBl + q * 4096 + w * 1024);
        }
        __syncthreads();
        bf16x8 ah[4], al[4], bh[4], bl[4];
        #pragma unroll
        for (int i = 0; i < 4; ++i) {
            int r = (wr * 64 + i * 16 + arow) * 32 + kch;
            ah[i] = *reinterpret_cast<const bf16x8*>(&sAh[r]);
            al[i] = *reinterpret_cast<const bf16x8*>(&sAl[r]);
        }
        #pragma unroll
        for (int j = 0; j < 4; ++j) {
            int r = (wc * 64 + j * 16 + arow) * 32 + kch;
            bh[j] = *reinterpret_cast<const bf16x8*>(&sBh[r]);
            bl[j] = *reinterpret_cast<const bf16x8*>(&sBl[r]);
        }
        #pragma unroll
        for (int i = 0; i < 4; ++i)
            #pragma unroll
            for (int j = 0; j < 4; ++j) {
                acc[i][j] = __builtin_amdgcn_mfma_f32_16x16x32_bf16(ah[i], bh[j], acc[i][j], 0, 0, 0);
                acc[i][j] = __builtin_amdgcn_mfma_f32_16x16x32_bf16(ah[i], bl[j], acc[i][j], 0, 0, 0);
                acc[i][j] = __builtin_amdgcn_mfma_f32_16x16x32_bf16(al[i], bh[j], acc[i][j], 0, 0, 0);
            }
        __syncthreads();
    }

    // epilogue: C row = n'', col = t; EO[b][t][n''] float4 stores
    const int ccol = lane & 15;
    const int rbase = (lane >> 4) * 4;
    float* eob = EO + (size_t)b_local * EO_E;
    #pragma unroll
    for (int i = 0; i < 4; ++i) {
        int nb = n0 + wr * 64 + i * 16 + rbase;
        #pragma unroll
        for (int j = 0; j < 4; ++j) {
            int t = t0 + wc * 64 + j * 16 + ccol;
            *reinterpret_cast<float4*>(&eob[(size_t)t * NFFT + nb]) =
                make_float4(acc[i][j][0], acc[i][j][1], acc[i][j][2], acc[i][j][3]);
        }
    }
}

// ---------------- gather: window * butterfly * OLA / env -> out ----------------
__global__ void gather_kernel(const float* __restrict__ EO,
                              const float* __restrict__ window,
                              float* __restrict__ out, int b0, int bcount) {
    int o = blockIdx.x * 256 + threadIdx.x;
    int s = o + PAD;
    int m = s >> 8, p = s & 255;
    float env = 1e-11f;
    float wv[4]; int tv[4]; int np[4]; float sg[4];
    #pragma unroll
    for (int j = 0; j < 4; ++j) {
        int t = m - j;
        bool ok = (t >= 0) && (t < T_);
        tv[j] = ok ? t : 0;
        np[j] = p + 256 * (j & 1);
        sg[j] = (j < 2) ? 1.f : -1.f;
        float ww = ok ? window[p + 256 * j] : 0.f;
        wv[j] = ww;
        env += ww * ww;
    }
    float inv = 1.0f / env;
    for (int bl = 0; bl < bcount; ++bl) {
        const float* eo = EO + (size_t)bl * EO_E;
        float y = 0.f;
        #pragma unroll
        for (int j = 0; j < 4; ++j) {
            const float* row = eo + (size_t)tv[j] * NFFT;
            float e = row[np[j]];
            float od = row[512 + np[j]];
            y = fmaf(wv[j], fmaf(sg[j], od, e), y);
        }
        out[(size_t)(b0 + bl) * OUTB + o] = y * inv;
    }
}

// ---------------- launch ----------------
extern "C" void kernel_launch(void* const* d_in, const int* in_sizes, int n_in,
                              void* d_out, int out_size, void* d_ws, size_t ws_size,
                              hipStream_t stream) {
    const float* x      = (const float*)d_in[0];
    const float* W      = (const float*)d_in[1];
    const float* bias   = (const float*)d_in[2];
    const float* window = (const float*)d_in[3];
    float* out = (float*)d_out;

    const size_t Ae  = (size_t)NFFT * KE;        //   589,824
    const size_t We  = (size_t)NW * H_;          //   294,912

    // bcount: largest that fits. Layout: [A|W|spec(4 bufs)|EO]  (no x buffers anymore)
    int bcount = B_;
    for (;;) {
        size_t need = (2 * Ae + 4 * We + 4 * (size_t)bcount * SE_E) * sizeof(ushort)
                    + (size_t)bcount * EO_E * sizeof(float);
        if (need <= ws_size || bcount == 1) break;
        bcount >>= 1;
    }

    ushort* Abh = (ushort*)d_ws;
    ushort* Abl = Abh + Ae;
    ushort* Wmh = Abl + Ae;
    ushort* Wml = Wmh + We;
    ushort* Wph = Wml + We;
    ushort* Wpl = Wph + We;
    ushort* SEh = Wpl + We;
    ushort* SEl = SEh + (size_t)bcount * SE_E;
    ushort* SOh = SEl + (size_t)bcount * SE_E;
    ushort* SOl = SOh + (size_t)bcount * SE_E;
    float*  EO  = (float*)(SOl + (size_t)bcount * SE_E);

    basis_kernel<<<(NFFT * KE) / 256, 256, 0, stream>>>(Abh, Abl);
    prepw_kernel<<<(NW * H_ + 255) / 256, 256, 0, stream>>>(W, Wmh, Wml, Wph, Wpl);

    for (int b0 = 0; b0 < B_; b0 += bcount) {
        dim3 ga(bcount * 32, 9);
        gemm_a_mfma<<<ga, 256, 0, stream>>>(x, Wmh, Wml, Wph, Wpl, bias,
                                            SEh, SEl, SOh, SOl, b0);
        dim3 ge(32, 8, bcount);
        gemm_eo_mfma<<<ge, 256, 0, stream>>>(Abh, Abl, SEh, SEl, SOh, SOl, EO);
        gather_kernel<<<OUTB / 256, 256, 0, stream>>>(EO, window, out, b0, bcount);
    }
}

// Round 10
// 325.679 us; speedup vs baseline: 1.2183x; 1.2183x over previous
//
#include <hip/hip_runtime.h>
#include <math.h>

#define B_  8
#define T_  4096
#define H_  512
#define FREQ 513
#define NW  576            // padded f (9 tiles of 64)
#define KE  576            // spec K: interleaved [re,im], padded; 9 tiles of 64
#define NFFT 1024
#define HOP 256
#define PAD 384
#define OUTB 1048576
#define CLAMP_MAXV 100.0f
#define SE_E ((size_t)T_ * KE)     // spec elems per batch (hi only now)
#define EO_E ((size_t)T_ * NFFT)   // EO floats per batch

typedef __attribute__((ext_vector_type(8))) short bf16x8;
typedef __attribute__((ext_vector_type(4))) float f32x4;

__device__ inline ushort f2bf(float v) {
    union { float f; unsigned u; } x; x.f = v;
    unsigned r = x.u + 0x7FFFu + ((x.u >> 16) & 1u);   // RNE
    return (ushort)(r >> 16);
}
__device__ inline float bf2f(ushort h) {
    union { unsigned u; float f; } x; x.u = ((unsigned)h) << 16;
    return x.f;
}

#define GLOAD_LDS16(g, l) __builtin_amdgcn_global_load_lds( \
    (const __attribute__((address_space(1))) unsigned int*)(g), \
    (__attribute__((address_space(3))) unsigned int*)(l), 16, 0, 0)

// ---------------- basis: Ab[r][c]; r<512: E half (k=2kk), r>=512: O half (k=2kk+1) ----------------
__global__ void basis_kernel(ushort* __restrict__ Abh, ushort* __restrict__ Abl) {
    int idx = blockIdx.x * 256 + threadIdx.x;   // [0, 1024*576)
    int r = idx / KE, c = idx - r * KE;
    int np = (r < 512) ? r : (r - 512);
    int kk = c >> 1;
    int k = (r < 512) ? (2 * kk) : (2 * kk + 1);
    float v = 0.f;
    bool valid = (r < 512) ? (kk <= 256) : (kk <= 255);
    if (valid) {
        int m = (np * k) & (NFFT - 1);
        float a = (float)m * 6.135923151542565e-3f;       // 2*pi/1024
        float sc = ((k == 0) || (k == 512)) ? (1.0f / NFFT) : (2.0f / NFFT);
        v = ((c & 1) ? -sinf(a) : cosf(a)) * sc;
    }
    ushort h = f2bf(v);
    Abh[idx] = h;
    Abl[idx] = f2bf(v - bf2f(h));
}

// ---------------- W prep: Wm/Wp [f(576)][k(512)] hi/lo bf16 ----------------
__global__ void prepw_kernel(const float* __restrict__ W,
                             ushort* __restrict__ Wmh, ushort* __restrict__ Wml,
                             ushort* __restrict__ Wph, ushort* __restrict__ Wpl) {
    int idx = blockIdx.x * 256 + threadIdx.x;
    if (idx >= NW * H_) return;
    int k = idx / NW, f = idx - k * NW;
    float vm = 0.f, vp = 0.f;
    if (f < FREQ) {
        vm = W[(size_t)k * (2 * FREQ) + f];
        vp = W[(size_t)k * (2 * FREQ) + FREQ + f];
    }
    size_t dst = (size_t)f * H_ + k;
    ushort h1 = f2bf(vm); Wmh[dst] = h1; Wml[dst] = f2bf(vm - bf2f(h1));
    ushort h2 = f2bf(vp); Wph[dst] = h2; Wpl[dst] = f2bf(vp - bf2f(h2));
}

// ---------------- GEMM A (MFMA split-bf16): tile 64t x 64f, K=512 ----------------
// grid: (bcount*64, 9); block 256 (4 waves 2x2, wave = 32t x 32f).
// Spec written TILED hi-only: buf[b][ftile][t][64].
__global__ __launch_bounds__(256) void gemm_a_mfma(
    const float* __restrict__ x,
    const ushort* __restrict__ Wmh, const ushort* __restrict__ Wml,
    const ushort* __restrict__ Wph, const ushort* __restrict__ Wpl,
    const float* __restrict__ bias,
    ushort* __restrict__ SEh, ushort* __restrict__ SOh, int b0)
{
    // 24KB: x hi/lo @0,2048; W @4096,6144,8192,10240 (ushort idx). Epilogue reuses [0,9216).
    __shared__ __attribute__((aligned(16))) ushort SH[12288];

    const int tid = threadIdx.x;
    const int lane = tid & 63;
    const int w = tid >> 6;
    const int wr = w >> 1, wc = w & 1;
    const int m0 = blockIdx.x * 64;      // chunk-local t row base
    const int f0 = blockIdx.y * 64;

    const int srow = tid >> 2;           // 0..63
    const int ssel = ((tid & 3) ^ ((tid >> 3) & 3)) * 8;
    const int arow = lane & 15;
    const int kch  = (((lane >> 4) ^ ((arow >> 1) & 3))) * 8;
    const int xcol = (tid & 3) * 8;

    f32x4 accM[2][2] = {};
    f32x4 accP[2][2] = {};

    const size_t xbase = (size_t)b0 * T_ + m0;
    char* pSH = (char*)SH;

    for (int k0 = 0; k0 < H_; k0 += 32) {
        // x: global fp32 -> regs (issue early)
        const float* xr = x + (xbase + srow) * H_ + k0 + xcol;
        float4 xa0 = *reinterpret_cast<const float4*>(xr);
        float4 xa1 = *reinterpret_cast<const float4*>(xr + 4);
        // W: global -> LDS direct (source pre-swizzled)
        size_t wo = (size_t)(f0 + srow) * H_ + k0 + ssel;
        GLOAD_LDS16(Wmh + wo, pSH + 8192  + w * 1024);
        GLOAD_LDS16(Wml + wo, pSH + 12288 + w * 1024);
        GLOAD_LDS16(Wph + wo, pSH + 16384 + w * 1024);
        GLOAD_LDS16(Wpl + wo, pSH + 20480 + w * 1024);
        // convert x -> hi/lo bf16, ds_write swizzled
        {
            float xv[8];
            *reinterpret_cast<float4*>(&xv[0]) = xa0;
            *reinterpret_cast<float4*>(&xv[4]) = xa1;
            bf16x8 vh, vl;
            #pragma unroll
            for (int e = 0; e < 8; ++e) {
                ushort h = f2bf(xv[e]);
                vh[e] = (short)h;
                vl[e] = (short)f2bf(xv[e] - bf2f(h));
            }
            int lo = srow * 32 + ssel;
            *reinterpret_cast<bf16x8*>(&SH[lo]) = vh;
            *reinterpret_cast<bf16x8*>(&SH[2048 + lo]) = vl;
        }
        __syncthreads();
        bf16x8 ah[2], al[2], bmh[2], bml[2], bph[2], bpl[2];
        #pragma unroll
        for (int i = 0; i < 2; ++i) {
            int r = (wr * 32 + i * 16 + arow) * 32 + kch;
            ah[i] = *reinterpret_cast<const bf16x8*>(&SH[r]);
            al[i] = *reinterpret_cast<const bf16x8*>(&SH[2048 + r]);
        }
        #pragma unroll
        for (int j = 0; j < 2; ++j) {
            int r = (wc * 32 + j * 16 + arow) * 32 + kch;
            bmh[j] = *reinterpret_cast<const bf16x8*>(&SH[4096 + r]);
            bml[j] = *reinterpret_cast<const bf16x8*>(&SH[6144 + r]);
            bph[j] = *reinterpret_cast<const bf16x8*>(&SH[8192 + r]);
            bpl[j] = *reinterpret_cast<const bf16x8*>(&SH[10240 + r]);
        }
        #pragma unroll
        for (int i = 0; i < 2; ++i)
            #pragma unroll
            for (int j = 0; j < 2; ++j) {
                accM[i][j] = __builtin_amdgcn_mfma_f32_16x16x32_bf16(ah[i], bmh[j], accM[i][j], 0, 0, 0);
                accM[i][j] = __builtin_amdgcn_mfma_f32_16x16x32_bf16(ah[i], bml[j], accM[i][j], 0, 0, 0);
                accM[i][j] = __builtin_amdgcn_mfma_f32_16x16x32_bf16(al[i], bmh[j], accM[i][j], 0, 0, 0);
                accP[i][j] = __builtin_amdgcn_mfma_f32_16x16x32_bf16(ah[i], bph[j], accP[i][j], 0, 0, 0);
                accP[i][j] = __builtin_amdgcn_mfma_f32_16x16x32_bf16(ah[i], bpl[j], accP[i][j], 0, 0, 0);
                accP[i][j] = __builtin_amdgcn_mfma_f32_16x16x32_bf16(al[i], bph[j], accP[i][j], 0, 0, 0);
            }
        __syncthreads();
    }

    // ---- epilogue: nonlinearity, single hi pass -> LDS transpose -> coalesced writes ----
    const int ccol = lane & 15;
    const int rbase = (lane >> 4) * 4;
    const int b_local = m0 >> 12;
    const int t00blk = m0 & (T_ - 1);
    const size_t specoff = (size_t)b_local * SE_E;
    const size_t tilebase = (size_t)blockIdx.y * T_ * 64;

    #pragma unroll
    for (int j = 0; j < 2; ++j) {
        int u = wc * 32 + j * 16 + ccol;
        int f = f0 + u;
        int par = u & 1;
        int kl = u & ~1;
        bool live = (f < FREQ);
        float bm = live ? bias[f] : 0.f;
        float bp = live ? bias[FREQ + f] : 0.f;
        #pragma unroll
        for (int i = 0; i < 2; ++i) {
            #pragma unroll
            for (int r = 0; r < 4; ++r) {
                float re = 0.f, im = 0.f;
                if (live) {
                    float mag = fminf(__expf(accM[i][j][r] + bm), CLAMP_MAXV);
                    float phv = accP[i][j][r] + bp;
                    float sp, cp; __sincosf(phv, &sp, &cp);
                    re = mag * cp; im = mag * sp;
                }
                int tl = wr * 32 + i * 16 + rbase + r;
                *reinterpret_cast<ushort2*>(&SH[par * 4608 + tl * 72 + kl]) =
                    make_ushort2(f2bf(re), f2bf(im));
            }
        }
    }
    __syncthreads();

    ushort* d0 = SEh + specoff + tilebase;
    ushort* d1 = SOh + specoff + tilebase;
    const int row0 = tid >> 3;     // 0..31
    const int c8 = (tid & 7) * 8;
    #pragma unroll
    for (int q2 = 0; q2 < 2; ++q2) {
        int row = q2 * 32 + row0;
        bf16x8 v0 = *reinterpret_cast<const bf16x8*>(&SH[row * 72 + c8]);
        bf16x8 v1 = *reinterpret_cast<const bf16x8*>(&SH[4608 + row * 72 + c8]);
        *reinterpret_cast<bf16x8*>(&d0[(size_t)(t00blk + row) * 64 + c8]) = v0;
        *reinterpret_cast<bf16x8*>(&d1[(size_t)(t00blk + row) * 64 + c8]) = v1;
    }
}

// ---------------- stage 1 GEMM (MFMA, 2-term): EO[b][t][n''] = (Ah+Al) . spec_hi ----------------
// grid: (64 t-tiles, 8 n-tiles, bcount); block 256 (4 waves 2x2, wave = 64n x 32t). Tile 128n x 64t.
__global__ __launch_bounds__(256) void gemm_eo_mfma(
    const ushort* __restrict__ Abh, const ushort* __restrict__ Abl,
    const ushort* __restrict__ SEh, const ushort* __restrict__ SOh,
    float* __restrict__ EO)
{
    __shared__ __attribute__((aligned(16))) ushort sAh[128 * 32];
    __shared__ __attribute__((aligned(16))) ushort sAl[128 * 32];
    __shared__ __attribute__((aligned(16))) ushort sBh[64 * 32];
    const int tid = threadIdx.x;
    const int lane = tid & 63;
    const int w = tid >> 6;
    const int wr = w >> 1, wc = w & 1;
    const int t0 = blockIdx.x * 64;
    const int n0 = blockIdx.y * 128;
    const int b_local = blockIdx.z;

    const ushort* Bsh = ((n0 < 512) ? SEh : SOh) + (size_t)b_local * SE_E;

    const int srow = tid >> 2;
    const int ssel = ((tid & 3) ^ ((tid >> 3) & 3)) * 8;
    const int arow = lane & 15;
    const int kch  = (((lane >> 4) ^ ((arow >> 1) & 3))) * 8;

    f32x4 acc[4][2] = {};
    char* pAh = (char*)sAh; char* pAl = (char*)sAl;
    char* pBh = (char*)sBh;

    for (int k0 = 0; k0 < KE; k0 += 32) {
        #pragma unroll
        for (int q = 0; q < 2; ++q) {
            size_t ao = (size_t)(n0 + q * 64 + srow) * KE + k0 + ssel;
            GLOAD_LDS16(Abh + ao, pAh + q * 4096 + w * 1024);
            GLOAD_LDS16(Abl + ao, pAl + q * 4096 + w * 1024);
        }
        size_t bo = ((size_t)(k0 >> 6) * T_ + t0 + srow) * 64 + (k0 & 32) + ssel;
        GLOAD_LDS16(Bsh + bo, pBh + w * 1024);
        __syncthreads();
        bf16x8 ah[4], al[4], bh[2];
        #pragma unroll
        for (int i = 0; i < 4; ++i) {
            int r = (wr * 64 + i * 16 + arow) * 32 + kch;
            ah[i] = *reinterpret_cast<const bf16x8*>(&sAh[r]);
            al[i] = *reinterpret_cast<const bf16x8*>(&sAl[r]);
        }
        #pragma unroll
        for (int j = 0; j < 2; ++j) {
            int r = (wc * 32 + j * 16 + arow) * 32 + kch;
            bh[j] = *reinterpret_cast<const bf16x8*>(&sBh[r]);
        }
        #pragma unroll
        for (int i = 0; i < 4; ++i)
            #pragma unroll
            for (int j = 0; j < 2; ++j) {
                acc[i][j] = __builtin_amdgcn_mfma_f32_16x16x32_bf16(ah[i], bh[j], acc[i][j], 0, 0, 0);
                acc[i][j] = __builtin_amdgcn_mfma_f32_16x16x32_bf16(al[i], bh[j], acc[i][j], 0, 0, 0);
            }
        __syncthreads();
    }

    // epilogue: C row = n'' (A rows), col = t (B rows); EO[b][t][n''] float4 stores
    const int ccol = lane & 15;
    const int rbase = (lane >> 4) * 4;
    float* eob = EO + (size_t)b_local * EO_E;
    #pragma unroll
    for (int i = 0; i < 4; ++i) {
        int nb = n0 + wr * 64 + i * 16 + rbase;
        #pragma unroll
        for (int j = 0; j < 2; ++j) {
            int t = t0 + wc * 32 + j * 16 + ccol;
            *reinterpret_cast<float4*>(&eob[(size_t)t * NFFT + nb]) =
                make_float4(acc[i][j][0], acc[i][j][1], acc[i][j][2], acc[i][j][3]);
        }
    }
}

// ---------------- gather: window * butterfly * OLA / env -> out ----------------
__global__ void gather_kernel(const float* __restrict__ EO,
                              const float* __restrict__ window,
                              float* __restrict__ out, int b0, int bcount) {
    int o = blockIdx.x * 256 + threadIdx.x;
    int s = o + PAD;
    int m = s >> 8, p = s & 255;
    float env = 1e-11f;
    float wv[4]; int tv[4]; int np[4]; float sg[4];
    #pragma unroll
    for (int j = 0; j < 4; ++j) {
        int t = m - j;
        bool ok = (t >= 0) && (t < T_);
        tv[j] = ok ? t : 0;
        np[j] = p + 256 * (j & 1);
        sg[j] = (j < 2) ? 1.f : -1.f;
        float ww = ok ? window[p + 256 * j] : 0.f;
        wv[j] = ww;
        env += ww * ww;
    }
    float inv = 1.0f / env;
    for (int bl = 0; bl < bcount; ++bl) {
        const float* eo = EO + (size_t)bl * EO_E;
        float y = 0.f;
        #pragma unroll
        for (int j = 0; j < 4; ++j) {
            const float* row = eo + (size_t)tv[j] * NFFT;
            float e = row[np[j]];
            float od = row[512 + np[j]];
            y = fmaf(wv[j], fmaf(sg[j], od, e), y);
        }
        out[(size_t)(b0 + bl) * OUTB + o] = y * inv;
    }
}

// ---------------- launch ----------------
extern "C" void kernel_launch(void* const* d_in, const int* in_sizes, int n_in,
                              void* d_out, int out_size, void* d_ws, size_t ws_size,
                              hipStream_t stream) {
    const float* x      = (const float*)d_in[0];
    const float* W      = (const float*)d_in[1];
    const float* bias   = (const float*)d_in[2];
    const float* window = (const float*)d_in[3];
    float* out = (float*)d_out;

    const size_t Ae  = (size_t)NFFT * KE;        //   589,824
    const size_t We  = (size_t)NW * H_;          //   294,912

    // bcount: largest that fits. Layout: [A(2)|W(4)|spec hi E,O|EO]
    int bcount = B_;
    for (;;) {
        size_t need = (2 * Ae + 4 * We + 2 * (size_t)bcount * SE_E) * sizeof(ushort)
                    + (size_t)bcount * EO_E * sizeof(float);
        if (need <= ws_size || bcount == 1) break;
        bcount >>= 1;
    }

    ushort* Abh = (ushort*)d_ws;
    ushort* Abl = Abh + Ae;
    ushort* Wmh = Abl + Ae;
    ushort* Wml = Wmh + We;
    ushort* Wph = Wml + We;
    ushort* Wpl = Wph + We;
    ushort* SEh = Wpl + We;
    ushort* SOh = SEh + (size_t)bcount * SE_E;
    float*  EO  = (float*)(SOh + (size_t)bcount * SE_E);

    basis_kernel<<<(NFFT * KE) / 256, 256, 0, stream>>>(Abh, Abl);
    prepw_kernel<<<(NW * H_ + 255) / 256, 256, 0, stream>>>(W, Wmh, Wml, Wph, Wpl);

    for (int b0 = 0; b0 < B_; b0 += bcount) {
        dim3 ga(bcount * 64, 9);
        gemm_a_mfma<<<ga, 256, 0, stream>>>(x, Wmh, Wml, Wph, Wpl, bias, SEh, SOh, b0);
        dim3 ge(64, 8, bcount);
        gemm_eo_mfma<<<ge, 256, 0, stream>>>(Abh, Abl, SEh, SOh, EO);
        gather_kernel<<<OUTB / 256, 256, 0, stream>>>(EO, window, out, b0, bcount);
    }
}

// Round 11
// 278.449 us; speedup vs baseline: 1.4250x; 1.1696x over previous
//
#include <hip/hip_runtime.h>
#include <hip/hip_fp16.h>
#include <math.h>

#define B_  8
#define T_  4096
#define H_  512
#define FREQ 513
#define NW  576            // padded f (9 tiles of 64)
#define KE  576            // spec K: interleaved [re,im], padded; 9 tiles of 64
#define NFFT 1024
#define HOP 256
#define PAD 384
#define OUTB 1048576
#define CLAMP_MAXV 100.0f
#define SE_E ((size_t)T_ * KE)     // spec elems per batch (hi only)
#define EO_E ((size_t)T_ * NFFT)   // EO elems per batch

typedef __attribute__((ext_vector_type(8))) short bf16x8;
typedef __attribute__((ext_vector_type(4))) float f32x4;

__device__ inline ushort f2bf(float v) {
    union { float f; unsigned u; } x; x.f = v;
    unsigned r = x.u + 0x7FFFu + ((x.u >> 16) & 1u);   // RNE
    return (ushort)(r >> 16);
}
__device__ inline float bf2f(ushort h) {
    union { unsigned u; float f; } x; x.u = ((unsigned)h) << 16;
    return x.f;
}

#define GLOAD_LDS16(g, l) __builtin_amdgcn_global_load_lds( \
    (const __attribute__((address_space(1))) unsigned int*)(g), \
    (__attribute__((address_space(3))) unsigned int*)(l), 16, 0, 0)

// ---------------- basis: Ab[r][c]; r<512: E half (k=2kk), r>=512: O half (k=2kk+1) ----------------
__global__ void basis_kernel(ushort* __restrict__ Abh, ushort* __restrict__ Abl) {
    int idx = blockIdx.x * 256 + threadIdx.x;   // [0, 1024*576)
    int r = idx / KE, c = idx - r * KE;
    int np = (r < 512) ? r : (r - 512);
    int kk = c >> 1;
    int k = (r < 512) ? (2 * kk) : (2 * kk + 1);
    float v = 0.f;
    bool valid = (r < 512) ? (kk <= 256) : (kk <= 255);
    if (valid) {
        int m = (np * k) & (NFFT - 1);
        float a = (float)m * 6.135923151542565e-3f;       // 2*pi/1024
        float sc = ((k == 0) || (k == 512)) ? (1.0f / NFFT) : (2.0f / NFFT);
        v = ((c & 1) ? -sinf(a) : cosf(a)) * sc;
    }
    ushort h = f2bf(v);
    Abh[idx] = h;
    Abl[idx] = f2bf(v - bf2f(h));
}

// ---------------- W prep: Wm/Wp [f(576)][k(512)] hi/lo bf16 ----------------
__global__ void prepw_kernel(const float* __restrict__ W,
                             ushort* __restrict__ Wmh, ushort* __restrict__ Wml,
                             ushort* __restrict__ Wph, ushort* __restrict__ Wpl) {
    int idx = blockIdx.x * 256 + threadIdx.x;
    if (idx >= NW * H_) return;
    int k = idx / NW, f = idx - k * NW;
    float vm = 0.f, vp = 0.f;
    if (f < FREQ) {
        vm = W[(size_t)k * (2 * FREQ) + f];
        vp = W[(size_t)k * (2 * FREQ) + FREQ + f];
    }
    size_t dst = (size_t)f * H_ + k;
    ushort h1 = f2bf(vm); Wmh[dst] = h1; Wml[dst] = f2bf(vm - bf2f(h1));
    ushort h2 = f2bf(vp); Wph[dst] = h2; Wpl[dst] = f2bf(vp - bf2f(h2));
}

// ---------------- GEMM A (MFMA split-bf16): tile 128t x 64f, K=512, fused x-convert ----------------
// grid: (bcount*32, 9); block 256 (4 waves 2x2). Spec written TILED hi-only: buf[b][ftile][t][64].
__global__ __launch_bounds__(256) void gemm_a_mfma(
    const float* __restrict__ x,
    const ushort* __restrict__ Wmh, const ushort* __restrict__ Wml,
    const ushort* __restrict__ Wph, const ushort* __restrict__ Wpl,
    const float* __restrict__ bias,
    ushort* __restrict__ SEh, ushort* __restrict__ SOh, int b0)
{
    // staging: x hi/lo @0,4096; W @8192..14336 (ushort idx) = 32KB. Epilogue: 2x9216 = 36.9KB.
    __shared__ __attribute__((aligned(16))) ushort SH[18432];

    const int tid = threadIdx.x;
    const int lane = tid & 63;
    const int w = tid >> 6;
    const int wr = w >> 1, wc = w & 1;
    const int m0 = blockIdx.x * 128;     // chunk-local t row base
    const int f0 = blockIdx.y * 64;

    const int srow = tid >> 2;           // 0..63
    const int ssel = ((tid & 3) ^ ((tid >> 3) & 3)) * 8;
    const int arow = lane & 15;
    const int kch  = (((lane >> 4) ^ ((arow >> 1) & 3))) * 8;
    const int xcol = (tid & 3) * 8;

    f32x4 accM[4][2] = {};
    f32x4 accP[4][2] = {};

    const size_t xbase = (size_t)b0 * T_ + m0;
    char* pSH = (char*)SH;

    for (int k0 = 0; k0 < H_; k0 += 32) {
        // x: global fp32 -> regs (issue early)
        float4 xa[2][2];
        #pragma unroll
        for (int q = 0; q < 2; ++q) {
            const float* xr = x + (xbase + q * 64 + srow) * H_ + k0 + xcol;
            xa[q][0] = *reinterpret_cast<const float4*>(xr);
            xa[q][1] = *reinterpret_cast<const float4*>(xr + 4);
        }
        // W: global -> LDS direct (source pre-swizzled)
        size_t wo = (size_t)(f0 + srow) * H_ + k0 + ssel;
        GLOAD_LDS16(Wmh + wo, pSH + 16384 + w * 1024);
        GLOAD_LDS16(Wml + wo, pSH + 20480 + w * 1024);
        GLOAD_LDS16(Wph + wo, pSH + 24576 + w * 1024);
        GLOAD_LDS16(Wpl + wo, pSH + 28672 + w * 1024);
        // convert x -> hi/lo bf16, ds_write swizzled
        #pragma unroll
        for (int q = 0; q < 2; ++q) {
            float xv[8];
            *reinterpret_cast<float4*>(&xv[0]) = xa[q][0];
            *reinterpret_cast<float4*>(&xv[4]) = xa[q][1];
            bf16x8 vh, vl;
            #pragma unroll
            for (int e = 0; e < 8; ++e) {
                ushort h = f2bf(xv[e]);
                vh[e] = (short)h;
                vl[e] = (short)f2bf(xv[e] - bf2f(h));
            }
            int lo = (q * 64 + srow) * 32 + ssel;
            *reinterpret_cast<bf16x8*>(&SH[lo]) = vh;
            *reinterpret_cast<bf16x8*>(&SH[4096 + lo]) = vl;
        }
        __syncthreads();
        bf16x8 ah[4], al[4], bmh[2], bml[2], bph[2], bpl[2];
        #pragma unroll
        for (int i = 0; i < 4; ++i) {
            int r = (wr * 64 + i * 16 + arow) * 32 + kch;
            ah[i] = *reinterpret_cast<const bf16x8*>(&SH[r]);
            al[i] = *reinterpret_cast<const bf16x8*>(&SH[4096 + r]);
        }
        #pragma unroll
        for (int j = 0; j < 2; ++j) {
            int r = (wc * 32 + j * 16 + arow) * 32 + kch;
            bmh[j] = *reinterpret_cast<const bf16x8*>(&SH[8192 + r]);
            bml[j] = *reinterpret_cast<const bf16x8*>(&SH[10240 + r]);
            bph[j] = *reinterpret_cast<const bf16x8*>(&SH[12288 + r]);
            bpl[j] = *reinterpret_cast<const bf16x8*>(&SH[14336 + r]);
        }
        #pragma unroll
        for (int i = 0; i < 4; ++i)
            #pragma unroll
            for (int j = 0; j < 2; ++j) {
                accM[i][j] = __builtin_amdgcn_mfma_f32_16x16x32_bf16(ah[i], bmh[j], accM[i][j], 0, 0, 0);
                accM[i][j] = __builtin_amdgcn_mfma_f32_16x16x32_bf16(ah[i], bml[j], accM[i][j], 0, 0, 0);
                accM[i][j] = __builtin_amdgcn_mfma_f32_16x16x32_bf16(al[i], bmh[j], accM[i][j], 0, 0, 0);
                accP[i][j] = __builtin_amdgcn_mfma_f32_16x16x32_bf16(ah[i], bph[j], accP[i][j], 0, 0, 0);
                accP[i][j] = __builtin_amdgcn_mfma_f32_16x16x32_bf16(ah[i], bpl[j], accP[i][j], 0, 0, 0);
                accP[i][j] = __builtin_amdgcn_mfma_f32_16x16x32_bf16(al[i], bph[j], accP[i][j], 0, 0, 0);
            }
        __syncthreads();
    }

    // ---- epilogue: nonlinearity, hi-only -> LDS transpose -> coalesced tiled writes ----
    const int ccol = lane & 15;
    const int rbase = (lane >> 4) * 4;
    const int b_local = m0 >> 12;
    const int t00blk = m0 & (T_ - 1);
    const size_t specoff = (size_t)b_local * SE_E;
    const size_t tilebase = (size_t)blockIdx.y * T_ * 64;

    #pragma unroll
    for (int j = 0; j < 2; ++j) {
        int u = wc * 32 + j * 16 + ccol;
        int f = f0 + u;
        int par = u & 1;
        int kl = u & ~1;
        bool live = (f < FREQ);
        float bm = live ? bias[f] : 0.f;
        float bp = live ? bias[FREQ + f] : 0.f;
        #pragma unroll
        for (int i = 0; i < 4; ++i) {
            #pragma unroll
            for (int r = 0; r < 4; ++r) {
                float re = 0.f, im = 0.f;
                if (live) {
                    float mag = fminf(__expf(accM[i][j][r] + bm), CLAMP_MAXV);
                    float phv = accP[i][j][r] + bp;
                    float sp, cp; __sincosf(phv, &sp, &cp);
                    re = mag * cp; im = mag * sp;
                }
                int tl = wr * 64 + i * 16 + rbase + r;
                *reinterpret_cast<ushort2*>(&SH[par * 9216 + tl * 72 + kl]) =
                    make_ushort2(f2bf(re), f2bf(im));
            }
        }
    }
    __syncthreads();

    ushort* d0 = SEh + specoff + tilebase;
    ushort* d1 = SOh + specoff + tilebase;
    const int row0 = tid >> 3;     // 0..31
    const int c8 = (tid & 7) * 8;
    #pragma unroll
    for (int q2 = 0; q2 < 4; ++q2) {
        int row = q2 * 32 + row0;
        bf16x8 v0 = *reinterpret_cast<const bf16x8*>(&SH[row * 72 + c8]);
        bf16x8 v1 = *reinterpret_cast<const bf16x8*>(&SH[9216 + row * 72 + c8]);
        *reinterpret_cast<bf16x8*>(&d0[(size_t)(t00blk + row) * 64 + c8]) = v0;
        *reinterpret_cast<bf16x8*>(&d1[(size_t)(t00blk + row) * 64 + c8]) = v1;
    }
}

// ---------------- stage 1 GEMM (MFMA, 2-term): EO[b][t][n''] = (Ah+Al).spec_hi, fp16 out -------
// grid: (64 t-tiles, 8 n-tiles, bcount); block 256 (4 waves 2x2). Tile 128n x 64t.
__global__ __launch_bounds__(256) void gemm_eo_mfma(
    const ushort* __restrict__ Abh, const ushort* __restrict__ Abl,
    const ushort* __restrict__ SEh, const ushort* __restrict__ SOh,
    __half* __restrict__ EO)
{
    __shared__ __attribute__((aligned(16))) ushort sAh[128 * 32];
    __shared__ __attribute__((aligned(16))) ushort sAl[128 * 32];
    __shared__ __attribute__((aligned(16))) ushort sBh[64 * 32];
    const int tid = threadIdx.x;
    const int lane = tid & 63;
    const int w = tid >> 6;
    const int wr = w >> 1, wc = w & 1;
    const int t0 = blockIdx.x * 64;
    const int n0 = blockIdx.y * 128;
    const int b_local = blockIdx.z;

    const ushort* Bsh = ((n0 < 512) ? SEh : SOh) + (size_t)b_local * SE_E;

    const int srow = tid >> 2;
    const int ssel = ((tid & 3) ^ ((tid >> 3) & 3)) * 8;
    const int arow = lane & 15;
    const int kch  = (((lane >> 4) ^ ((arow >> 1) & 3))) * 8;

    f32x4 acc[4][2] = {};
    char* pAh = (char*)sAh; char* pAl = (char*)sAl;
    char* pBh = (char*)sBh;

    for (int k0 = 0; k0 < KE; k0 += 32) {
        #pragma unroll
        for (int q = 0; q < 2; ++q) {
            size_t ao = (size_t)(n0 + q * 64 + srow) * KE + k0 + ssel;
            GLOAD_LDS16(Abh + ao, pAh + q * 4096 + w * 1024);
            GLOAD_LDS16(Abl + ao, pAl + q * 4096 + w * 1024);
        }
        size_t bo = ((size_t)(k0 >> 6) * T_ + t0 + srow) * 64 + (k0 & 32) + ssel;
        GLOAD_LDS16(Bsh + bo, pBh + w * 1024);
        __syncthreads();
        bf16x8 ah[4], al[4], bh[2];
        #pragma unroll
        for (int i = 0; i < 4; ++i) {
            int r = (wr * 64 + i * 16 + arow) * 32 + kch;
            ah[i] = *reinterpret_cast<const bf16x8*>(&sAh[r]);
            al[i] = *reinterpret_cast<const bf16x8*>(&sAl[r]);
        }
        #pragma unroll
        for (int j = 0; j < 2; ++j) {
            int r = (wc * 32 + j * 16 + arow) * 32 + kch;
            bh[j] = *reinterpret_cast<const bf16x8*>(&sBh[r]);
        }
        #pragma unroll
        for (int i = 0; i < 4; ++i)
            #pragma unroll
            for (int j = 0; j < 2; ++j) {
                acc[i][j] = __builtin_amdgcn_mfma_f32_16x16x32_bf16(ah[i], bh[j], acc[i][j], 0, 0, 0);
                acc[i][j] = __builtin_amdgcn_mfma_f32_16x16x32_bf16(al[i], bh[j], acc[i][j], 0, 0, 0);
            }
        __syncthreads();
    }

    // epilogue: C row = n'', col = t; EO[b][t][n''] as fp16, 8B stores
    const int ccol = lane & 15;
    const int rbase = (lane >> 4) * 4;
    __half* eob = EO + (size_t)b_local * EO_E;
    #pragma unroll
    for (int i = 0; i < 4; ++i) {
        int nb = n0 + wr * 64 + i * 16 + rbase;
        #pragma unroll
        for (int j = 0; j < 2; ++j) {
            int t = t0 + wc * 32 + j * 16 + ccol;
            __half hv[4];
            hv[0] = __float2half(acc[i][j][0]);
            hv[1] = __float2half(acc[i][j][1]);
            hv[2] = __float2half(acc[i][j][2]);
            hv[3] = __float2half(acc[i][j][3]);
            *reinterpret_cast<short4*>(&eob[(size_t)t * NFFT + nb]) =
                *reinterpret_cast<short4*>(hv);
        }
    }
}

// ---------------- gather: window * butterfly * OLA / env -> out ----------------
__global__ void gather_kernel(const __half* __restrict__ EO,
                              const float* __restrict__ window,
                              float* __restrict__ out, int b0, int bcount) {
    int o = blockIdx.x * 256 + threadIdx.x;
    int s = o + PAD;
    int m = s >> 8, p = s & 255;
    float env = 1e-11f;
    float wv[4]; int tv[4]; int np[4]; float sg[4];
    #pragma unroll
    for (int j = 0; j < 4; ++j) {
        int t = m - j;
        bool ok = (t >= 0) && (t < T_);
        tv[j] = ok ? t : 0;
        np[j] = p + 256 * (j & 1);
        sg[j] = (j < 2) ? 1.f : -1.f;
        float ww = ok ? window[p + 256 * j] : 0.f;
        wv[j] = ww;
        env += ww * ww;
    }
    float inv = 1.0f / env;
    for (int bl = 0; bl < bcount; ++bl) {
        const __half* eo = EO + (size_t)bl * EO_E;
        float y = 0.f;
        #pragma unroll
        for (int j = 0; j < 4; ++j) {
            const __half* row = eo + (size_t)tv[j] * NFFT;
            float e = __half2float(row[np[j]]);
            float od = __half2float(row[512 + np[j]]);
            y = fmaf(wv[j], fmaf(sg[j], od, e), y);
        }
        out[(size_t)(b0 + bl) * OUTB + o] = y * inv;
    }
}

// ---------------- launch ----------------
extern "C" void kernel_launch(void* const* d_in, const int* in_sizes, int n_in,
                              void* d_out, int out_size, void* d_ws, size_t ws_size,
                              hipStream_t stream) {
    const float* x      = (const float*)d_in[0];
    const float* W      = (const float*)d_in[1];
    const float* bias   = (const float*)d_in[2];
    const float* window = (const float*)d_in[3];
    float* out = (float*)d_out;

    const size_t Ae  = (size_t)NFFT * KE;        //   589,824
    const size_t We  = (size_t)NW * H_;          //   294,912

    // bcount: largest that fits. Layout: [A(2)|W(4)|spec hi E,O|EO(fp16)]
    int bcount = B_;
    for (;;) {
        size_t need = (2 * Ae + 4 * We + 2 * (size_t)bcount * SE_E) * sizeof(ushort)
                    + (size_t)bcount * EO_E * sizeof(__half);
        if (need <= ws_size || bcount == 1) break;
        bcount >>= 1;
    }

    ushort* Abh = (ushort*)d_ws;
    ushort* Abl = Abh + Ae;
    ushort* Wmh = Abl + Ae;
    ushort* Wml = Wmh + We;
    ushort* Wph = Wml + We;
    ushort* Wpl = Wph + We;
    ushort* SEh = Wpl + We;
    ushort* SOh = SEh + (size_t)bcount * SE_E;
    __half* EO  = (__half*)(SOh + (size_t)bcount * SE_E);

    basis_kernel<<<(NFFT * KE) / 256, 256, 0, stream>>>(Abh, Abl);
    prepw_kernel<<<(NW * H_ + 255) / 256, 256, 0, stream>>>(W, Wmh, Wml, Wph, Wpl);

    for (int b0 = 0; b0 < B_; b0 += bcount) {
        dim3 ga(bcount * 32, 9);
        gemm_a_mfma<<<ga, 256, 0, stream>>>(x, Wmh, Wml, Wph, Wpl, bias, SEh, SOh, b0);
        dim3 ge(64, 8, bcount);
        gemm_eo_mfma<<<ge, 256, 0, stream>>>(Abh, Abl, SEh, SOh, EO);
        gather_kernel<<<OUTB / 256, 256, 0, stream>>>(EO, window, out, b0, bcount);
    }
}